// Round 1
// baseline (419.264 us; speedup 1.0000x reference)
//
#include <hip/hip_runtime.h>

// Fused 4-layer MLP (2 -> 1024 -> 512 -> 256 -> 3), N = 262144, fp32 I/O.
// R8: occupancy restructure. R7 ran 1 block/CU (116 VGPR + 128 AGPR acc = 244
// regs/wave -> 2 waves/SIMD, Occupancy 22.8%, MfmaUtil 45%): every barrier
// idled the whole CU, and 2 waves/SIMD can't hide af(L2 ~200cy)/bf(LDS ~120cy)
// latency. R8 halves the block row-tile to 64 rows so acc2 = 2jt x 2mt = 64
// AGPR; __launch_bounds__(512,4) targets <=128 regs/wave = 4 waves/SIMD =
// 2 blocks/CU resident. Double-buffered 2x32KB chunk slabs merge layer1 into
// the layer2 phase (one barrier per chunk); single-pass tail (64-row h2 = 64KB
// slab). Barriers 16 -> 8, each hideable under the co-resident block.
// fp16 MFMA 32x32x16, fp32 accumulate, transposed layers D[feat][batch].

typedef _Float16 f16;
typedef f16 f16x8 __attribute__((ext_vector_type(8)));
typedef f16 f16x4 __attribute__((ext_vector_type(4)));
typedef float f32x16 __attribute__((ext_vector_type(16)));

#define MFMA(a, b, c) __builtin_amdgcn_mfma_f32_32x32x16_f16((a), (b), (c), 0, 0, 0)

// ws layout in 16-byte units (f16x8):
//  W1F : [16 jt][64 ks][64 lane]            ->      0 .. 65536
//  W2F : [ 8 jt][32 ks][64 lane]            ->  65536 .. 81920
//  W3F : [16 ks][64 lane]                   ->  81920 .. 82944
//  P0F : [32 k1t][64 lane] (layer1 A frag)  ->  82944 .. 84992
//  B1F : [16 jt][64 lane]                   ->  84992 .. 86016
//  B2F : [ 8 jt][64 lane]                   ->  86016 .. 86528
#define U_W1F 0
#define U_W2F 65536
#define U_W3F 81920
#define U_P0F 82944
#define U_B1F 84992
#define U_B2F 86016
#define U_TOTAL 86528

__global__ void prep_kernel(const float* __restrict__ W0, const float* __restrict__ b0,
                            const float* __restrict__ W1, const float* __restrict__ b1,
                            const float* __restrict__ W2, const float* __restrict__ b2,
                            const float* __restrict__ W3, f16* __restrict__ ws)
{
    int u = blockIdx.x * 256 + threadIdx.x;
    if (u >= U_TOTAL) return;
    int lane = u & 63;
    int l31 = lane & 31;
    int q = lane >> 5;
    f16x8 v;
#pragma unroll
    for (int e = 0; e < 8; ++e) v[e] = (f16)0.f;

    if (u < U_W2F) {                       // W1F: W1 is [1024][512]
        int jt = u >> 12, ks = (u >> 6) & 63;
        int j = jt * 32 + l31;
        int kb = ks * 16 + q * 8;
        const float* p = W1 + (size_t)kb * 512 + j;
#pragma unroll
        for (int e = 0; e < 8; ++e) v[e] = (f16)p[(size_t)e * 512];
    } else if (u < U_W3F) {                // W2F: W2 is [512][256]
        int t = u - U_W2F;
        int jt = t >> 11, ks = (t >> 6) & 31;
        int j = jt * 32 + l31;
        int kb = ks * 16 + q * 8;
        const float* p = W2 + (size_t)kb * 256 + j;
#pragma unroll
        for (int e = 0; e < 8; ++e) v[e] = (f16)p[(size_t)e * 256];
    } else if (u < U_P0F) {                // W3F: W3 is [256][3], pad j>=3 with 0
        int t = u - U_W3F;
        int ks = t >> 6;
        int j = l31;
        int kb = ks * 16 + q * 8;
        if (j < 3) {
            const float* p = W3 + (size_t)kb * 3 + j;
#pragma unroll
            for (int e = 0; e < 8; ++e) v[e] = (f16)p[(size_t)e * 3];
        }
    } else if (u < U_B1F) {                // P0F: layer-1 A frag with hi/lo split + bias
        int t = u - U_P0F;
        int jt = t >> 6;
        int j = jt * 32 + l31;
        if (q == 0) {
            float w00 = W0[j], w01 = W0[1024 + j], bb = b0[j];
            f16 w00h = (f16)w00, w01h = (f16)w01, bh = (f16)bb;
            v[0] = w00h; v[1] = w01h; v[2] = bh;
            v[3] = w00h; v[4] = w01h;                       // pair with x_lo
            v[5] = (f16)(w00 - (float)w00h);                // w_lo * x_hi
            v[6] = (f16)(w01 - (float)w01h);
            v[7] = (f16)(bb - (float)bh);                   // bias residual * 1
        }
    } else if (u < U_B2F) {                // B1F
        int t = u - U_B1F;
        int jt = t >> 6;
        int j = jt * 32 + l31;
        if (q == 0) v[0] = (f16)b1[j];
    } else {                               // B2F
        int t = u - U_B2F;
        int jt = t >> 6;
        int j = jt * 32 + l31;
        if (q == 0) v[0] = (f16)b2[j];
    }
    ((f16x8*)ws)[u] = v;
}

// ---- LDS slab helpers. Slab rows: [m][k] f16, row stride rs bytes.
// XOR swizzle at 8-byte granularity: phys_dw = dw ^ ((m&15)<<1).
// 2-way-max bank conflicts (free) for both b64 writes and reads.
__device__ __forceinline__ void slab_write4(unsigned char* lds, int m, int dw /*even*/,
                                            int rs, f16x4 val)
{
    int s = (m & 15) << 1;
    *(f16x4*)(lds + (size_t)m * rs + (size_t)((dw ^ s) << 2)) = val;
}

__device__ __forceinline__ f16x8 slab_read8(const unsigned char* lds, int m, int dw /*mult of 4*/,
                                            int rs)
{
    int s = (m & 15) << 1;
    f16x4 lo = *(const f16x4*)(lds + (size_t)m * rs + (size_t)((dw ^ s) << 2));
    f16x4 hi = *(const f16x4*)(lds + (size_t)m * rs + (size_t)(((dw + 2) ^ s) << 2));
    union { f16x8 v; f16x4 p[2]; } u;
    u.p[0] = lo; u.p[1] = hi;
    return u.v;
}

__device__ __forceinline__ f16x4 relu_pack4(const f32x16& d, int t)
{
    f16x4 pk;
#pragma unroll
    for (int r = 0; r < 4; ++r) {
        float v = d[4 * t + r];
        pk[r] = (f16)(v > 0.f ? v : 0.f);
    }
    return pk;
}

__global__ __launch_bounds__(512, 4)
void mlp_kernel(const float* __restrict__ X, const float* __restrict__ b3,
                const f16* __restrict__ ws, float* __restrict__ out)
{
    const f16x8* W1F = (const f16x8*)ws + U_W1F;
    const f16x8* W2F = (const f16x8*)ws + U_W2F;
    const f16x8* W3F = (const f16x8*)ws + U_W3F;
    const f16x8* P0F = (const f16x8*)ws + U_P0F;
    const f16x8* B1F = (const f16x8*)ws + U_B1F;
    const f16x8* B2F = (const f16x8*)ws + U_B2F;

    // 2 x 32KB double-buffered chunk slabs (64 rows x 256 f16, rs=512B);
    // tail reuses the whole 64KB as one h2 slab (64 rows x 512 f16, rs=1024B).
    __shared__ __align__(16) unsigned char lds[65536];

    const int tid  = threadIdx.x;
    const int w    = tid >> 6;       // wave 0..7
    const int lane = tid & 63;
    const int l31  = lane & 31;
    const int q    = lane >> 5;
    const size_t rowbase = (size_t)blockIdx.x * 64;

    f32x16 zero16;
#pragma unroll
    for (int i = 0; i < 16; ++i) zero16[i] = 0.f;

    // ones frag for bias-init MFMAs
    f16x8 ones;
#pragma unroll
    for (int e = 0; e < 8; ++e) ones[e] = (f16)0.f;
    if (q == 0) ones[0] = (f16)1.f;

    // X frags for both m-tiles (hi/lo split -> layer 1 ~exact); 8 regs
    f16x8 xfrag[2];
#pragma unroll
    for (int mt = 0; mt < 2; ++mt) {
        f16x8 v;
#pragma unroll
        for (int e = 0; e < 8; ++e) v[e] = (f16)0.f;
        if (q == 0) {
            float2 xv = ((const float2*)X)[rowbase + mt * 32 + l31];
            f16 x0h = (f16)xv.x, x1h = (f16)xv.y;
            v[0] = x0h; v[1] = x1h; v[2] = (f16)1.f;
            v[3] = (f16)(xv.x - (float)x0h);
            v[4] = (f16)(xv.y - (float)x1h);
            v[5] = x0h; v[6] = x1h; v[7] = (f16)1.f;
        }
        xfrag[mt] = v;
    }

    // Layer-2 ownership: wave w -> j-tiles 2w, 2w+1; both m-tiles.
    const int jt0 = w * 2;
    f32x16 acc2[2][2];   // [ji][mt] = 64 regs
#pragma unroll
    for (int ji = 0; ji < 2; ++ji) {
        f32x16 binit = MFMA(B1F[(jt0 + ji) * 64 + lane], ones, zero16);
        acc2[ji][0] = binit;
        acc2[ji][1] = binit;
    }

    // prologue: layer1 chunk 0 -> buf0. Wave w owns chunk-local k1-tile w.
    {
        f16x8 af1 = P0F[w * 64 + lane];
        int kb = w * 32 + 4 * q;              // h1 feat (chunk-local)
#pragma unroll
        for (int mt = 0; mt < 2; ++mt) {
            f32x16 d = MFMA(af1, xfrag[mt], zero16);
            int m = mt * 32 + l31;            // batch row
#pragma unroll
            for (int t = 0; t < 4; ++t)
                slab_write4(lds, m, (kb + 8 * t) >> 1, 512, relu_pack4(d, t));
        }
    }
    __syncthreads();

    // ---- fused layer1+layer2 pipeline: K chunked 4 x 256, dbuf slabs,
    // one barrier per chunk. layer1(c+1) rides inside layer2(c)'s phase.
    for (int c = 0; c < 4; ++c) {
        const unsigned char* rb = lds + (size_t)(c & 1) * 32768;
        // layer 2 partial K: 16 ks; 2 af (L2), 2 bf (LDS), 4 MFMA per ks
#pragma unroll 4
        for (int ks = 0; ks < 16; ++ks) {
            int ksg = c * 16 + ks;
            f16x8 af0 = W1F[(jt0 * 64 + ksg) * 64 + lane];
            f16x8 af1 = W1F[((jt0 + 1) * 64 + ksg) * 64 + lane];
            int dw = (ks * 16 + q * 8) >> 1;
            f16x8 bf0 = slab_read8(rb, l31, dw, 512);
            f16x8 bf1 = slab_read8(rb, 32 + l31, dw, 512);
            acc2[0][0] = MFMA(af0, bf0, acc2[0][0]);
            acc2[0][1] = MFMA(af0, bf1, acc2[0][1]);
            acc2[1][0] = MFMA(af1, bf0, acc2[1][0]);
            acc2[1][1] = MFMA(af1, bf1, acc2[1][1]);
        }
        // layer 1 for next chunk -> other buffer (placed after the ks loop to
        // keep transient d/pack liveness off the af/bf window; other waves'
        // MFMAs cover its latency at 4 waves/SIMD)
        if (c < 3) {
            unsigned char* wb = lds + (size_t)((c + 1) & 1) * 32768;
            f16x8 af1 = P0F[((c + 1) * 8 + w) * 64 + lane];
            int kb = w * 32 + 4 * q;
#pragma unroll
            for (int mt = 0; mt < 2; ++mt) {
                f32x16 d = MFMA(af1, xfrag[mt], zero16);
                int m = mt * 32 + l31;
#pragma unroll
                for (int t = 0; t < 4; ++t)
                    slab_write4(wb, m, (kb + 8 * t) >> 1, 512, relu_pack4(d, t));
            }
        }
        __syncthreads();
    }

    // ---- tail, single pass (64 rows): stage h2 (64 rows x 512 feats, rs=1024B)
    // wave w -> j-tiles jt0, jt0+1
#pragma unroll
    for (int ji = 0; ji < 2; ++ji) {
        int jb = (jt0 + ji) * 32 + 4 * q;
#pragma unroll
        for (int mt = 0; mt < 2; ++mt) {
            int m = mt * 32 + l31;
#pragma unroll
            for (int t = 0; t < 4; ++t)
                slab_write4(lds, m, (jb + 8 * t) >> 1, 1024,
                            relu_pack4(acc2[ji][mt], t));
        }
    }
    __syncthreads();

    // layer 3: wave w -> j-tile w (of 8), both 32-row tiles; K=512
    f32x16 acc3[2];
    {
        f32x16 binit = MFMA(B2F[w * 64 + lane], ones, zero16);
        acc3[0] = binit;
        acc3[1] = binit;
    }
#pragma unroll 4
    for (int ks = 0; ks < 32; ++ks) {
        f16x8 af = W2F[(w * 32 + ks) * 64 + lane];
        int dw = (ks * 16 + q * 8) >> 1;
        f16x8 bf0 = slab_read8(lds, l31, dw, 1024);
        f16x8 bf1 = slab_read8(lds, 32 + l31, dw, 1024);
        acc3[0] = MFMA(af, bf0, acc3[0]);
        acc3[1] = MFMA(af, bf1, acc3[1]);
    }
    __syncthreads();

    // stage h3 (64 rows x 256 feats, rs=512B)
    {
        int jb = w * 32 + 4 * q;
#pragma unroll
        for (int mt = 0; mt < 2; ++mt) {
            int m = mt * 32 + l31;
#pragma unroll
            for (int t = 0; t < 4; ++t)
                slab_write4(lds, m, (jb + 8 * t) >> 1, 512,
                            relu_pack4(acc3[mt], t));
        }
    }
    __syncthreads();

    // layer 4: waves 0,1 -> the two 32-row tiles (j padded, 3 valid).
    // Idle waves here overlap the co-resident block's main loop.
    if (w < 2) {
        f32x16 acc4 = zero16;
#pragma unroll 4
        for (int ks = 0; ks < 16; ++ks) {
            f16x8 af = W3F[ks * 64 + lane];
            f16x8 bf = slab_read8(lds, w * 32 + l31, (ks * 16 + q * 8) >> 1, 512);
            acc4 = MFMA(af, bf, acc4);
        }
        if (q == 0) {
            size_t gm = rowbase + w * 32 + l31;
            out[gm * 3 + 0] = acc4[0] + b3[0];
            out[gm * 3 + 1] = acc4[1] + b3[1];
            out[gm * 3 + 2] = acc4[2] + b3[2];
        }
    }
}

extern "C" void kernel_launch(void* const* d_in, const int* in_sizes, int n_in,
                              void* d_out, int out_size, void* d_ws, size_t ws_size,
                              hipStream_t stream)
{
    const float* X  = (const float*)d_in[0];
    const float* W0 = (const float*)d_in[1];
    const float* b0 = (const float*)d_in[2];
    const float* W1 = (const float*)d_in[3];
    const float* b1 = (const float*)d_in[4];
    const float* W2 = (const float*)d_in[5];
    const float* b2 = (const float*)d_in[6];
    const float* W3 = (const float*)d_in[7];
    const float* b3 = (const float*)d_in[8];
    f16* ws = (f16*)d_ws;

    int N = in_sizes[0] / 2;          // 262144
    int nblk = N / 64;                // 4096

    prep_kernel<<<(U_TOTAL + 255) / 256, 256, 0, stream>>>(W0, b0, W1, b1, W2, b2, W3, ws);
    mlp_kernel<<<nblk, 512, 0, stream>>>(X, b3, ws, (float*)d_out);
}

// Round 2
// 404.890 us; speedup vs baseline: 1.0355x; 1.0355x over previous
//
#include <hip/hip_runtime.h>

// Fused 4-layer MLP (2 -> 1024 -> 512 -> 256 -> 3), N = 262144, fp32 I/O.
// R9: intensity + occupancy together. R7 (128 rows, 8 waves) had good weight
// reuse but 2 waves/SIMD (244 regs). R8 (64 rows, 8 waves) had 4 waves/SIMD
// but doubled the W1 L2 stream (5.5 GB; ~39 TB/s needed at matrix-bound,
// over the per-XCD L2 ceiling) -> both stuck at ~50% MfmaUtil, ~360 us.
// R9: 1024-thread block (16 waves), 128 rows/block. Wave owns 1 jt x 4 mt ->
// acc2[4] = 64 AGPR; per ks ONE af load feeds 4 MFMAs (half of R8's af
// bytes/FLOP, total weight traffic 2.8 GB). __launch_bounds__(1024,4) keeps
// the 128-reg/wave budget -> 4 waves/SIMD. LDS 128 KB: 2x64KB dbuf chunk
// slabs, tail reuses all 128 KB for the h2 slab (single-pass tail).
// Manual 1-ahead prefetch on the af (W1F/W2F) L2 streams.
// fp16 MFMA 32x32x16, fp32 accumulate, transposed layers D[feat][batch].

typedef _Float16 f16;
typedef f16 f16x8 __attribute__((ext_vector_type(8)));
typedef f16 f16x4 __attribute__((ext_vector_type(4)));
typedef float f32x16 __attribute__((ext_vector_type(16)));

#define MFMA(a, b, c) __builtin_amdgcn_mfma_f32_32x32x16_f16((a), (b), (c), 0, 0, 0)

// ws layout in 16-byte units (f16x8):
//  W1F : [16 jt][64 ks][64 lane]            ->      0 .. 65536
//  W2F : [ 8 jt][32 ks][64 lane]            ->  65536 .. 81920
//  W3F : [16 ks][64 lane]                   ->  81920 .. 82944
//  P0F : [32 k1t][64 lane] (layer1 A frag)  ->  82944 .. 84992
//  B1F : [16 jt][64 lane]                   ->  84992 .. 86016
//  B2F : [ 8 jt][64 lane]                   ->  86016 .. 86528
#define U_W1F 0
#define U_W2F 65536
#define U_W3F 81920
#define U_P0F 82944
#define U_B1F 84992
#define U_B2F 86016
#define U_TOTAL 86528

__global__ void prep_kernel(const float* __restrict__ W0, const float* __restrict__ b0,
                            const float* __restrict__ W1, const float* __restrict__ b1,
                            const float* __restrict__ W2, const float* __restrict__ b2,
                            const float* __restrict__ W3, f16* __restrict__ ws)
{
    int u = blockIdx.x * 256 + threadIdx.x;
    if (u >= U_TOTAL) return;
    int lane = u & 63;
    int l31 = lane & 31;
    int q = lane >> 5;
    f16x8 v;
#pragma unroll
    for (int e = 0; e < 8; ++e) v[e] = (f16)0.f;

    if (u < U_W2F) {                       // W1F: W1 is [1024][512]
        int jt = u >> 12, ks = (u >> 6) & 63;
        int j = jt * 32 + l31;
        int kb = ks * 16 + q * 8;
        const float* p = W1 + (size_t)kb * 512 + j;
#pragma unroll
        for (int e = 0; e < 8; ++e) v[e] = (f16)p[(size_t)e * 512];
    } else if (u < U_W3F) {                // W2F: W2 is [512][256]
        int t = u - U_W2F;
        int jt = t >> 11, ks = (t >> 6) & 31;
        int j = jt * 32 + l31;
        int kb = ks * 16 + q * 8;
        const float* p = W2 + (size_t)kb * 256 + j;
#pragma unroll
        for (int e = 0; e < 8; ++e) v[e] = (f16)p[(size_t)e * 256];
    } else if (u < U_P0F) {                // W3F: W3 is [256][3], pad j>=3 with 0
        int t = u - U_W3F;
        int ks = t >> 6;
        int j = l31;
        int kb = ks * 16 + q * 8;
        if (j < 3) {
            const float* p = W3 + (size_t)kb * 3 + j;
#pragma unroll
            for (int e = 0; e < 8; ++e) v[e] = (f16)p[(size_t)e * 3];
        }
    } else if (u < U_B1F) {                // P0F: layer-1 A frag with hi/lo split + bias
        int t = u - U_P0F;
        int jt = t >> 6;
        int j = jt * 32 + l31;
        if (q == 0) {
            float w00 = W0[j], w01 = W0[1024 + j], bb = b0[j];
            f16 w00h = (f16)w00, w01h = (f16)w01, bh = (f16)bb;
            v[0] = w00h; v[1] = w01h; v[2] = bh;
            v[3] = w00h; v[4] = w01h;                       // pair with x_lo
            v[5] = (f16)(w00 - (float)w00h);                // w_lo * x_hi
            v[6] = (f16)(w01 - (float)w01h);
            v[7] = (f16)(bb - (float)bh);                   // bias residual * 1
        }
    } else if (u < U_B2F) {                // B1F
        int t = u - U_B1F;
        int jt = t >> 6;
        int j = jt * 32 + l31;
        if (q == 0) v[0] = (f16)b1[j];
    } else {                               // B2F
        int t = u - U_B2F;
        int jt = t >> 6;
        int j = jt * 32 + l31;
        if (q == 0) v[0] = (f16)b2[j];
    }
    ((f16x8*)ws)[u] = v;
}

// ---- LDS slab helpers. Slab rows: [m][k] f16, row stride rs bytes.
// XOR swizzle at 8-byte granularity: phys_dw = dw ^ ((m&15)<<1).
// 2-way-max bank conflicts (free) for both b64 writes and reads.
__device__ __forceinline__ void slab_write4(unsigned char* lds, int m, int dw /*even*/,
                                            int rs, f16x4 val)
{
    int s = (m & 15) << 1;
    *(f16x4*)(lds + (size_t)m * rs + (size_t)((dw ^ s) << 2)) = val;
}

__device__ __forceinline__ f16x8 slab_read8(const unsigned char* lds, int m, int dw /*mult of 4*/,
                                            int rs)
{
    int s = (m & 15) << 1;
    f16x4 lo = *(const f16x4*)(lds + (size_t)m * rs + (size_t)((dw ^ s) << 2));
    f16x4 hi = *(const f16x4*)(lds + (size_t)m * rs + (size_t)(((dw + 2) ^ s) << 2));
    union { f16x8 v; f16x4 p[2]; } u;
    u.p[0] = lo; u.p[1] = hi;
    return u.v;
}

__device__ __forceinline__ f16x4 relu_pack4(const f32x16& d, int t)
{
    f16x4 pk;
#pragma unroll
    for (int r = 0; r < 4; ++r) {
        float v = d[4 * t + r];
        pk[r] = (f16)(v > 0.f ? v : 0.f);
    }
    return pk;
}

__global__ __launch_bounds__(1024, 4)
void mlp_kernel(const float* __restrict__ X, const float* __restrict__ b3,
                const f16* __restrict__ ws, float* __restrict__ out)
{
    const f16x8* W1F = (const f16x8*)ws + U_W1F;
    const f16x8* W2F = (const f16x8*)ws + U_W2F;
    const f16x8* W3F = (const f16x8*)ws + U_W3F;
    const f16x8* P0F = (const f16x8*)ws + U_P0F;
    const f16x8* B1F = (const f16x8*)ws + U_B1F;
    const f16x8* B2F = (const f16x8*)ws + U_B2F;

    // 2 x 64KB double-buffered chunk slabs (128 rows x 256 f16, rs=512B);
    // tail reuses the whole 128KB as one h2 slab (128 rows x 512 f16, rs=1024B).
    __shared__ __align__(16) unsigned char lds[131072];

    const int tid  = threadIdx.x;
    const int w    = tid >> 6;       // wave 0..15
    const int lane = tid & 63;
    const int l31  = lane & 31;
    const int q    = lane >> 5;
    const int k1t  = w & 7;          // layer-1 k-tile / layer-3 j-tile
    const int mh   = w >> 3;         // m-half for layer-1 / layer-3
    const size_t rowbase = (size_t)blockIdx.x * 128;

    f32x16 zero16;
#pragma unroll
    for (int i = 0; i < 16; ++i) zero16[i] = 0.f;

    // ones frag for bias-init MFMAs
    f16x8 ones;
#pragma unroll
    for (int e = 0; e < 8; ++e) ones[e] = (f16)0.f;
    if (q == 0) ones[0] = (f16)1.f;

    // X frags for this wave's two m-tiles only (hi/lo split -> layer 1 ~exact)
    f16x8 xfrag[2];
#pragma unroll
    for (int mi = 0; mi < 2; ++mi) {
        int mt = mh * 2 + mi;
        f16x8 v;
#pragma unroll
        for (int e = 0; e < 8; ++e) v[e] = (f16)0.f;
        if (q == 0) {
            float2 xv = ((const float2*)X)[rowbase + mt * 32 + l31];
            f16 x0h = (f16)xv.x, x1h = (f16)xv.y;
            v[0] = x0h; v[1] = x1h; v[2] = (f16)1.f;
            v[3] = (f16)(xv.x - (float)x0h);
            v[4] = (f16)(xv.y - (float)x1h);
            v[5] = x0h; v[6] = x1h; v[7] = (f16)1.f;
        }
        xfrag[mi] = v;
    }

    // Layer-2 ownership: wave w -> j-tile w (of 16), all 4 m-tiles.
    f32x16 acc2[4];   // [mt] = 64 AGPR
    {
        f32x16 binit = MFMA(B1F[w * 64 + lane], ones, zero16);
#pragma unroll
        for (int mt = 0; mt < 4; ++mt) acc2[mt] = binit;
    }

    // prologue: layer1 chunk 0 -> buf0. Wave w: k1-tile k1t, m-tiles mh*2..+1.
    {
        f16x8 af1 = P0F[k1t * 64 + lane];
        int kb = k1t * 32 + 4 * q;            // h1 feat (chunk-local)
#pragma unroll
        for (int mi = 0; mi < 2; ++mi) {
            f32x16 d = MFMA(af1, xfrag[mi], zero16);
            int m = (mh * 2 + mi) * 32 + l31; // batch row
#pragma unroll
            for (int t = 0; t < 4; ++t)
                slab_write4(lds, m, (kb + 8 * t) >> 1, 512, relu_pack4(d, t));
        }
    }
    __syncthreads();

    // af stream pointer: W1F[(w*64 + ksg)*64 + lane], 1-ahead prefetch.
    const f16x8* __restrict__ afp = W1F + (size_t)(w * 64) * 64 + lane;
    f16x8 afn = afp[0];

    // ---- fused layer1+layer2 pipeline: K chunked 4 x 256, dbuf slabs,
    // one barrier per chunk. layer1(c+1) rides inside layer2(c)'s phase.
    for (int c = 0; c < 4; ++c) {
        const unsigned char* rb = lds + (size_t)(c & 1) * 65536;
        // layer 2 partial K: 16 ks; 1 af (L2, prefetched), 4 bf (LDS), 4 MFMA
#pragma unroll 4
        for (int ks = 0; ks < 16; ++ks) {
            f16x8 af = afn;
            afp += 64;
            afn = *afp;   // final prefetch overruns W1F into W2F: harmless
            int dw = (ks * 16 + q * 8) >> 1;
            f16x8 bf0 = slab_read8(rb, l31, dw, 512);
            f16x8 bf1 = slab_read8(rb, 32 + l31, dw, 512);
            f16x8 bf2 = slab_read8(rb, 64 + l31, dw, 512);
            f16x8 bf3 = slab_read8(rb, 96 + l31, dw, 512);
            acc2[0] = MFMA(af, bf0, acc2[0]);
            acc2[1] = MFMA(af, bf1, acc2[1]);
            acc2[2] = MFMA(af, bf2, acc2[2]);
            acc2[3] = MFMA(af, bf3, acc2[3]);
        }
        // layer 1 for next chunk -> other buffer
        if (c < 3) {
            unsigned char* wb = lds + (size_t)((c + 1) & 1) * 65536;
            f16x8 af1 = P0F[((c + 1) * 8 + k1t) * 64 + lane];
            int kb = k1t * 32 + 4 * q;
#pragma unroll
            for (int mi = 0; mi < 2; ++mi) {
                f32x16 d = MFMA(af1, xfrag[mi], zero16);
                int m = (mh * 2 + mi) * 32 + l31;
#pragma unroll
                for (int t = 0; t < 4; ++t)
                    slab_write4(wb, m, (kb + 8 * t) >> 1, 512, relu_pack4(d, t));
            }
        }
        __syncthreads();
    }

    // ---- tail, single pass (128 rows): stage h2 (128 rows x 512 feats,
    // rs=1024B = 128KB). Wave w -> j-tile w, all 4 m-tiles.
    {
        int jb = w * 32 + 4 * q;
#pragma unroll
        for (int mt = 0; mt < 4; ++mt) {
            int m = mt * 32 + l31;
#pragma unroll
            for (int t = 0; t < 4; ++t)
                slab_write4(lds, m, (jb + 8 * t) >> 1, 1024,
                            relu_pack4(acc2[mt], t));
        }
    }
    __syncthreads();

    // layer 3: wave w -> j-tile k1t (of 8), m-half mh; K=512
    f32x16 acc3[2];
    {
        f32x16 binit = MFMA(B2F[k1t * 64 + lane], ones, zero16);
        acc3[0] = binit;
        acc3[1] = binit;
    }
    {
        const f16x8* __restrict__ afp3 = W2F + (size_t)(k1t * 32) * 64 + lane;
        f16x8 af3n = afp3[0];
#pragma unroll 4
        for (int ks = 0; ks < 32; ++ks) {
            f16x8 af = af3n;
            afp3 += 64;
            af3n = *afp3;   // final prefetch overruns W2F into W3F: harmless
            int dw = (ks * 16 + q * 8) >> 1;
            f16x8 bf0 = slab_read8(lds, mh * 64 + l31, dw, 1024);
            f16x8 bf1 = slab_read8(lds, mh * 64 + 32 + l31, dw, 1024);
            acc3[0] = MFMA(af, bf0, acc3[0]);
            acc3[1] = MFMA(af, bf1, acc3[1]);
        }
    }
    __syncthreads();

    // stage h3 (128 rows x 256 feats, rs=512B = 64KB)
    {
        int jb = k1t * 32 + 4 * q;
#pragma unroll
        for (int u = 0; u < 2; ++u) {
            int m = mh * 64 + u * 32 + l31;
#pragma unroll
            for (int t = 0; t < 4; ++t)
                slab_write4(lds, m, (jb + 8 * t) >> 1, 512,
                            relu_pack4(acc3[u], t));
        }
    }
    __syncthreads();

    // layer 4: waves 0..3 -> the four 32-row tiles (j padded, 3 valid).
    if (w < 4) {
        f32x16 acc4 = zero16;
#pragma unroll 4
        for (int ks = 0; ks < 16; ++ks) {
            f16x8 af = W3F[ks * 64 + lane];
            f16x8 bf = slab_read8(lds, w * 32 + l31, (ks * 16 + q * 8) >> 1, 512);
            acc4 = MFMA(af, bf, acc4);
        }
        if (q == 0) {
            size_t gm = rowbase + w * 32 + l31;
            out[gm * 3 + 0] = acc4[0] + b3[0];
            out[gm * 3 + 1] = acc4[1] + b3[1];
            out[gm * 3 + 2] = acc4[2] + b3[2];
        }
    }
}

extern "C" void kernel_launch(void* const* d_in, const int* in_sizes, int n_in,
                              void* d_out, int out_size, void* d_ws, size_t ws_size,
                              hipStream_t stream)
{
    const float* X  = (const float*)d_in[0];
    const float* W0 = (const float*)d_in[1];
    const float* b0 = (const float*)d_in[2];
    const float* W1 = (const float*)d_in[3];
    const float* b1 = (const float*)d_in[4];
    const float* W2 = (const float*)d_in[5];
    const float* b2 = (const float*)d_in[6];
    const float* W3 = (const float*)d_in[7];
    const float* b3 = (const float*)d_in[8];
    f16* ws = (f16*)d_ws;

    int N = in_sizes[0] / 2;          // 262144
    int nblk = N / 128;               // 2048

    prep_kernel<<<(U_TOTAL + 255) / 256, 256, 0, stream>>>(W0, b0, W1, b1, W2, b2, W3, ws);
    mlp_kernel<<<nblk, 1024, 0, stream>>>(X, b3, ws, (float*)d_out);
}